// Round 7
// baseline (304.254 us; speedup 1.0000x reference)
//
#include <hip/hip_runtime.h>
#include <math.h>

#define B_    8
#define M_    2048
#define FIN_  256
#define FOUT_ 128
#define ALPHA_ 0.2f
#define NEG_INF_ -9.0e15f

typedef unsigned short u16;
typedef unsigned int   u32;
typedef unsigned long long u64;
typedef __attribute__((ext_vector_type(8))) short bf16x8;
typedef __attribute__((ext_vector_type(4))) float f32x4;

static __device__ __forceinline__ u16 f2bf(float f) {
  union { float f; unsigned u; } v; v.f = f;
  unsigned r = v.u + 0x7FFFu + ((v.u >> 16) & 1u);   // RNE bf16
  return (u16)(r >> 16);
}

// -------- kernel 0: Wt[f][k] = bf16(W[k][f])  (128x256) --------
__global__ __launch_bounds__(256) void k_wt(const float* __restrict__ W,
                                            u16* __restrict__ Wt) {
  const int id = blockIdx.x * 256 + threadIdx.x;   // 32768 total
  const int f = id >> 8;
  const int k = id & 255;
  Wt[f * FIN_ + k] = f2bf(W[(size_t)k * FOUT_ + f]);
}

// -------- kernel 0b: adjacency -> bitmask (134 MB -> 4.2 MB) --------
// grid 2048 x 256. Wave w handles 4096 consecutive adj elements (64 steps x 64 lanes).
__global__ __launch_bounds__(256) void k_pack(const int* __restrict__ adj,
                                              u64* __restrict__ mask64) {
  const int wid = (blockIdx.x * 256 + threadIdx.x) >> 6;  // global wave id
  const int l   = threadIdx.x & 63;
  const size_t base = (size_t)wid * 4096 + l;
#pragma unroll 1
  for (int kk = 0; kk < 4; ++kk) {
#pragma unroll
    for (int k = 0; k < 16; ++k) {
      const int step = kk * 16 + k;
      int v = adj[base + (size_t)step * 64];
      u64 bal = __ballot(v > 0);                 // bit l = (adj[.. + l] > 0)
      if (l == 0) mask64[(size_t)wid * 64 + step] = bal;
    }
  }
}

// -------- kernel 1: h = x@W via MFMA (fp32->bf16 in-reg); fused f1/f2; h^T bf16 --------
// grid 1024 x 128 thr. Block = 16 rows; wave w owns feats w*64..+63 (ft=4 frags).
__global__ __launch_bounds__(128) void k_xw(const float* __restrict__ x,
                                            const u16* __restrict__ Wt,
                                            const float* __restrict__ a,
                                            u16* __restrict__ ht,
                                            float* __restrict__ f1,
                                            float* __restrict__ f2) {
  int blk = blockIdx.x;
  blk = (blk & 7) * 128 + (blk >> 3);          // XCD swizzle (1024%8==0)
  const int b    = blk >> 7;
  const int row0 = (blk & 127) * 16;           // within batch
  const int rowg = b * M_ + row0;              // global flat row
  const int tid  = threadIdx.x;
  const int w  = tid >> 6;
  const int l  = tid & 63;
  const int lr = l & 15;
  const int g  = l >> 4;
  const int fbase = w * 64;

  f32x4 acc[4];
#pragma unroll
  for (int ft = 0; ft < 4; ++ft) acc[ft] = (f32x4){0.f, 0.f, 0.f, 0.f};

  const float* xr = x + (size_t)(rowg + lr) * FIN_;
#pragma unroll
  for (int ks = 0; ks < 8; ++ks) {
    float4 xa = *(const float4*)(xr + ks * 32 + g * 8);
    float4 xc = *(const float4*)(xr + ks * 32 + g * 8 + 4);
    bf16x8 af;
    af[0] = (short)f2bf(xa.x); af[1] = (short)f2bf(xa.y);
    af[2] = (short)f2bf(xa.z); af[3] = (short)f2bf(xa.w);
    af[4] = (short)f2bf(xc.x); af[5] = (short)f2bf(xc.y);
    af[6] = (short)f2bf(xc.z); af[7] = (short)f2bf(xc.w);
#pragma unroll
    for (int ft = 0; ft < 4; ++ft) {
      bf16x8 bf = *(const bf16x8*)(Wt + (fbase + ft * 16 + lr) * FIN_ + ks * 32 + g * 8);
      acc[ft] = __builtin_amdgcn_mfma_f32_16x16x32_bf16(af, bf, acc[ft], 0, 0, 0);
    }
  }

  // ---- fused f1/f2 (per-wave partial over 64 feats, combine via LDS) ----
  __shared__ float sf1[2][16], sf2[2][16];
  float v1[4] = {0.f, 0.f, 0.f, 0.f};
  float v2[4] = {0.f, 0.f, 0.f, 0.f};
#pragma unroll
  for (int ft = 0; ft < 4; ++ft) {
    const float a1v = a[fbase + ft * 16 + lr];
    const float a2v = a[FOUT_ + fbase + ft * 16 + lr];
#pragma unroll
    for (int j = 0; j < 4; ++j) {
      v1[j] += acc[ft][j] * a1v;
      v2[j] += acc[ft][j] * a2v;
    }
  }
#pragma unroll
  for (int off = 1; off < 16; off <<= 1) {
#pragma unroll
    for (int j = 0; j < 4; ++j) {
      v1[j] += __shfl_xor(v1[j], off);
      v2[j] += __shfl_xor(v2[j], off);
    }
  }
  if (lr == 0) {
#pragma unroll
    for (int j = 0; j < 4; ++j) {
      sf1[w][g * 4 + j] = v1[j];
      sf2[w][g * 4 + j] = v2[j];
    }
  }

  // ---- h^T transpose via LDS ----
  __shared__ float hs[16][132];
#pragma unroll
  for (int ft = 0; ft < 4; ++ft)
#pragma unroll
    for (int j = 0; j < 4; ++j)
      hs[g * 4 + j][fbase + ft * 16 + lr] = acc[ft][j];
  __syncthreads();

  if (tid < 16) {
    f1[rowg + tid] = sf1[0][tid] + sf1[1][tid];
    f2[rowg + tid] = sf2[0][tid] + sf2[1][tid];
  }
  const int f = tid;
  union { u16 u[16]; uint4 q[2]; } hb;
#pragma unroll
  for (int i = 0; i < 16; ++i) hb.u[i] = f2bf(hs[i][f]);
  u16* dst = ht + (size_t)(b * FOUT_ + f) * M_ + row0;
  *(uint4*)(dst)     = hb.q[0];
  *(uint4*)(dst + 8) = hb.q[1];
}

// -------- kernel 2: fused masked-softmax attention, MFMA PV --------
// grid 1024 x 256 thr (4 waves, wave w owns feats w*32..+31). 16 rows/block.
// ONE barrier/iter; P + sscale double-buffered; mask/f2/V prefetched one iter
// ahead. All loop data (mask 4.2MB, ht 4.2MB, f2) is L2/L3-resident -> latency
// covered by the 1-iter prefetch; adj HBM stream handled by k_pack.
__global__ __launch_bounds__(256) void k_attn(const u16* __restrict__ ht,
                                              const u32* __restrict__ mask32,
                                              const float* __restrict__ f1,
                                              const float* __restrict__ f2,
                                              float* __restrict__ out) {
  int blk = blockIdx.x;
  blk = (blk & 7) * 128 + (blk >> 3);         // XCD swizzle (1024%8==0)
  const int b    = blk >> 7;
  const int row0 = (blk & 127) * 16;
  const int tid = threadIdx.x;
  const int w  = tid >> 6;
  const int l  = tid & 63;
  const int lr = l & 15;
  const int g  = l >> 4;
  const int r  = tid >> 4;                    // 16 rows x 16 threads
  const int ts = tid & 15;

  __shared__ __align__(16) u16 P[2][16][128];  // double-buffered bf16 P, XOR swizzle
  __shared__ float sscale[2][16];              // double-buffered rescale factor
  __shared__ float smx[16], ssum[16], f1s[16];

  if (tid < 16) {
    smx[tid]  = -INFINITY;
    ssum[tid] = 0.f;
    f1s[tid]  = f1[b * M_ + row0 + tid];
  }

  f32x4 acc0 = (f32x4){0.f, 0.f, 0.f, 0.f};
  f32x4 acc1 = (f32x4){0.f, 0.f, 0.f, 0.f};

  const int fbase = w * 32;
  // mask words for this row: 64 u32 per row; this thread uses word (it*4 + ts/4)
  const u32* mp   = mask32 + ((size_t)b * M_ + row0 + r) * 64 + (ts >> 2);
  const int mshift = (ts & 3) * 8;
  const float* fp = f2 + b * M_ + ts * 8;
  const u16* hp0  = ht + (size_t)(b * FOUT_ + fbase + lr) * M_ + g * 8;
  const u16* hp1  = hp0 + 16 * M_;
  char* Pb = (char*)P;

  // prefetch chunk 0: mask, f2, V
  u32    mwA = mp[0];
  float4 fvA = *(const float4*)(fp);
  float4 fvB = *(const float4*)(fp + 4);
  bf16x8 vbuf0[8], vbuf1[8];
#pragma unroll
  for (int ks = 0; ks < 4; ++ks) {
    vbuf0[ks]     = *(const bf16x8*)(hp0 + ks * 32);
    vbuf0[4 + ks] = *(const bf16x8*)(hp1 + ks * 32);
  }

  __syncthreads();

  auto iter = [&](int it, bf16x8 (&vcur)[8], bf16x8 (&vnxt)[8]) {
    const int bi = it & 1;
    // ---- scores + online softmax from prefetched regs ----
    const u32   mbyte = (mwA >> mshift) & 0xffu;
    const float fv[8] = {fvA.x, fvA.y, fvA.z, fvA.w, fvB.x, fvB.y, fvB.z, fvB.w};
    const float f1r = f1s[r];
    float s[8];
#pragma unroll
    for (int i = 0; i < 8; ++i) {
      float z = f1r + fv[i];
      float e = z > 0.f ? z : ALPHA_ * z;
      s[i] = (mbyte & (1u << i)) ? e : NEG_INF_;
    }
    float cmax = s[0];
#pragma unroll
    for (int i = 1; i < 8; ++i) cmax = fmaxf(cmax, s[i]);
#pragma unroll
    for (int off = 1; off < 16; off <<= 1) cmax = fmaxf(cmax, __shfl_xor(cmax, off));
    const float m_old = smx[r];
    const float m_new = fmaxf(m_old, cmax);
    const float scl   = __expf(m_old - m_new);
    float psum = 0.f;
#pragma unroll
    for (int i = 0; i < 8; ++i) {
      float p = __expf(s[i] - m_new);
      s[i] = p;
      psum += p;
    }
#pragma unroll
    for (int off = 1; off < 16; off <<= 1) psum += __shfl_xor(psum, off);
    if (ts == 0) {
      smx[r]        = m_new;
      ssum[r]       = ssum[r] * scl + psum;
      sscale[bi][r] = scl;
    }
    // ---- P -> bf16, swizzled LDS write into buffer bi ----
    union { u16 u[8]; uint4 q; } pw;
#pragma unroll
    for (int i = 0; i < 8; ++i) pw.u[i] = f2bf(s[i]);
    *(uint4*)(Pb + bi * 4096 + r * 256 + ((ts ^ (r & 7)) << 4)) = pw.q;
    __syncthreads();   // ONE barrier per iteration

    // ---- issue next chunk's loads (L2-latency; full iteration of cover) ----
    const int itn = (it + 1 < 16) ? (it + 1) : 0;   // harmless tail reload
    mwA = mp[itn * 4];
    fvA = *(const float4*)(fp + itn * 128);
    fvB = *(const float4*)(fp + itn * 128 + 4);
#pragma unroll
    for (int ks = 0; ks < 4; ++ks) {
      vnxt[ks]     = *(const bf16x8*)(hp0 + itn * 128 + ks * 32);
      vnxt[4 + ks] = *(const bf16x8*)(hp1 + itn * 128 + ks * 32);
    }
    // ---- MFMA PV from current regs + P[bi] ----
    f32x4 scv = { sscale[bi][g * 4],     sscale[bi][g * 4 + 1],
                  sscale[bi][g * 4 + 2], sscale[bi][g * 4 + 3] };
    acc0 *= scv;
    acc1 *= scv;
#pragma unroll
    for (int ks = 0; ks < 4; ++ks) {
      bf16x8 af = *(const bf16x8*)(Pb + bi * 4096 + lr * 256 +
                                   (((ks * 4 + g) ^ (lr & 7)) << 4));
      acc0 = __builtin_amdgcn_mfma_f32_16x16x32_bf16(af, vcur[ks],     acc0, 0, 0, 0);
      acc1 = __builtin_amdgcn_mfma_f32_16x16x32_bf16(af, vcur[4 + ks], acc1, 0, 0, 0);
    }
  };

#pragma unroll 1
  for (int it = 0; it < 16; it += 2) {
    iter(it,     vbuf0, vbuf1);
    iter(it + 1, vbuf1, vbuf0);
  }

  // ---- epilogue: 1/sum, ELU, store ----
  f32x4 inv = { 1.f / ssum[g * 4], 1.f / ssum[g * 4 + 1],
                1.f / ssum[g * 4 + 2], 1.f / ssum[g * 4 + 3] };
#pragma unroll
  for (int j = 0; j < 4; ++j) {
    const size_t orow = ((size_t)b * M_ + row0 + g * 4 + j) * FOUT_;
    float t0 = acc0[j] * inv[j];
    float t1 = acc1[j] * inv[j];
    out[orow + fbase + lr]      = t0 > 0.f ? t0 : __expf(t0) - 1.f;
    out[orow + fbase + 16 + lr] = t1 > 0.f ? t1 : __expf(t1) - 1.f;
  }
}

extern "C" void kernel_launch(void* const* d_in, const int* in_sizes, int n_in,
                              void* d_out, int out_size, void* d_ws, size_t ws_size,
                              hipStream_t stream) {
  const float* x   = (const float*)d_in[0];
  const int*   adj = (const int*)d_in[1];
  const float* W   = (const float*)d_in[2];
  const float* a   = (const float*)d_in[3];
  float* out = (float*)d_out;

  char* ws = (char*)d_ws;
  u16*   Wt   = (u16*)ws;                         // 64 KB
  float* f1   = (float*)(ws + 65536);             // 64 KB
  float* f2   = (float*)(ws + 131072);            // 64 KB
  u16*   ht   = (u16*)(ws + 196608);              // 8.4 MB  [B][128][2048] bf16
  u64*   mask = (u64*)(ws + 196608 + 8388608);    // 4.2 MB  bitmask

  hipLaunchKernelGGL(k_wt,   dim3(128),  dim3(256), 0, stream, W, Wt);
  hipLaunchKernelGGL(k_pack, dim3(2048), dim3(256), 0, stream, adj, mask);
  hipLaunchKernelGGL(k_xw,   dim3(1024), dim3(128), 0, stream, x, Wt, a, ht, f1, f2);
  hipLaunchKernelGGL(k_attn, dim3(1024), dim3(256), 0, stream, ht, (const u32*)mask, f1, f2, out);
}

// Round 9
// 290.772 us; speedup vs baseline: 1.0464x; 1.0464x over previous
//
#include <hip/hip_runtime.h>
#include <math.h>

#define B_    8
#define M_    2048
#define FIN_  256
#define FOUT_ 128
#define ALPHA_ 0.2f
#define NEG_INF_ -9.0e15f

typedef unsigned short u16;
typedef unsigned int   u32;
typedef __attribute__((ext_vector_type(8))) short bf16x8;
typedef __attribute__((ext_vector_type(4))) float f32x4;

static __device__ __forceinline__ u16 f2bf(float f) {
  union { float f; unsigned u; } v; v.f = f;
  unsigned r = v.u + 0x7FFFu + ((v.u >> 16) & 1u);   // RNE bf16
  return (u16)(r >> 16);
}

// -------- kernel 0: Wt[f][k] = bf16(W[k][f])  (128x256) --------
__global__ __launch_bounds__(256) void k_wt(const float* __restrict__ W,
                                            u16* __restrict__ Wt) {
  const int id = blockIdx.x * 256 + threadIdx.x;   // 32768 total
  const int f = id >> 8;
  const int k = id & 255;
  Wt[f * FIN_ + k] = f2bf(W[(size_t)k * FOUT_ + f]);
}

// -------- kernel 1: h = x@W via MFMA (fp32->bf16 in-reg); fused f1/f2; h^T bf16 --------
// grid 1024 x 128 thr. Block = 16 rows; wave w owns feats w*64..+63 (ft=4 frags).
__global__ __launch_bounds__(128) void k_xw(const float* __restrict__ x,
                                            const u16* __restrict__ Wt,
                                            const float* __restrict__ a,
                                            u16* __restrict__ ht,
                                            float* __restrict__ f1,
                                            float* __restrict__ f2) {
  int blk = blockIdx.x;
  blk = (blk & 7) * 128 + (blk >> 3);          // XCD swizzle (1024%8==0)
  const int b    = blk >> 7;
  const int row0 = (blk & 127) * 16;           // within batch
  const int rowg = b * M_ + row0;              // global flat row
  const int tid  = threadIdx.x;
  const int w  = tid >> 6;
  const int l  = tid & 63;
  const int lr = l & 15;
  const int g  = l >> 4;
  const int fbase = w * 64;

  f32x4 acc[4];
#pragma unroll
  for (int ft = 0; ft < 4; ++ft) acc[ft] = (f32x4){0.f, 0.f, 0.f, 0.f};

  const float* xr = x + (size_t)(rowg + lr) * FIN_;
#pragma unroll
  for (int ks = 0; ks < 8; ++ks) {
    float4 xa = *(const float4*)(xr + ks * 32 + g * 8);
    float4 xc = *(const float4*)(xr + ks * 32 + g * 8 + 4);
    bf16x8 af;
    af[0] = (short)f2bf(xa.x); af[1] = (short)f2bf(xa.y);
    af[2] = (short)f2bf(xa.z); af[3] = (short)f2bf(xa.w);
    af[4] = (short)f2bf(xc.x); af[5] = (short)f2bf(xc.y);
    af[6] = (short)f2bf(xc.z); af[7] = (short)f2bf(xc.w);
#pragma unroll
    for (int ft = 0; ft < 4; ++ft) {
      bf16x8 bf = *(const bf16x8*)(Wt + (fbase + ft * 16 + lr) * FIN_ + ks * 32 + g * 8);
      acc[ft] = __builtin_amdgcn_mfma_f32_16x16x32_bf16(af, bf, acc[ft], 0, 0, 0);
    }
  }

  // ---- fused f1/f2 (per-wave partial over 64 feats, combine via LDS) ----
  __shared__ float sf1[2][16], sf2[2][16];
  float v1[4] = {0.f, 0.f, 0.f, 0.f};
  float v2[4] = {0.f, 0.f, 0.f, 0.f};
#pragma unroll
  for (int ft = 0; ft < 4; ++ft) {
    const float a1v = a[fbase + ft * 16 + lr];
    const float a2v = a[FOUT_ + fbase + ft * 16 + lr];
#pragma unroll
    for (int j = 0; j < 4; ++j) {
      v1[j] += acc[ft][j] * a1v;
      v2[j] += acc[ft][j] * a2v;
    }
  }
#pragma unroll
  for (int off = 1; off < 16; off <<= 1) {
#pragma unroll
    for (int j = 0; j < 4; ++j) {
      v1[j] += __shfl_xor(v1[j], off);
      v2[j] += __shfl_xor(v2[j], off);
    }
  }
  if (lr == 0) {
#pragma unroll
    for (int j = 0; j < 4; ++j) {
      sf1[w][g * 4 + j] = v1[j];
      sf2[w][g * 4 + j] = v2[j];
    }
  }

  // ---- h^T transpose via LDS ----
  __shared__ float hs[16][132];
#pragma unroll
  for (int ft = 0; ft < 4; ++ft)
#pragma unroll
    for (int j = 0; j < 4; ++j)
      hs[g * 4 + j][fbase + ft * 16 + lr] = acc[ft][j];
  __syncthreads();

  if (tid < 16) {
    f1[rowg + tid] = sf1[0][tid] + sf1[1][tid];
    f2[rowg + tid] = sf2[0][tid] + sf2[1][tid];
  }
  const int f = tid;
  union { u16 u[16]; uint4 q[2]; } hb;
#pragma unroll
  for (int i = 0; i < 16; ++i) hb.u[i] = f2bf(hs[i][f]);
  u16* dst = ht + (size_t)(b * FOUT_ + f) * M_ + row0;
  *(uint4*)(dst)     = hb.q[0];
  *(uint4*)(dst + 8) = hb.q[1];
}

// -------- kernel 2: barrier-free fused masked-softmax attention --------
// grid 1024 x 256. Block = 16 rows; wave w independently handles col quarter
// [w*512, w*512+512) for ALL 128 feats. Score computed directly in MFMA
// A-frag layout (lane: row=l&15, k=(l>>4)*8..+7) -> P never leaves registers;
// no LDS/barrier in the loop. Row max/sum via shfl_xor(16|32). Defer-max
// (THR=8) keeps rescale rare & wave-uniform. End: 4-wave (m,l,acc) merge in LDS.
__global__ __launch_bounds__(256) void k_attn(const u16* __restrict__ ht,
                                              const int* __restrict__ adj,
                                              const float* __restrict__ f1,
                                              const float* __restrict__ f2,
                                              float* __restrict__ out) {
  int blk = blockIdx.x;
  blk = (blk & 7) * 128 + (blk >> 3);         // XCD swizzle (1024%8==0)
  const int b    = blk >> 7;
  const int row0 = (blk & 127) * 16;
  const int tid = threadIdx.x;
  const int w  = tid >> 6;                    // col quarter
  const int l  = tid & 63;
  const int lr = l & 15;                      // A-frag row
  const int g  = l >> 4;                      // A-frag k-group

  const int colbase = w * 512;
  const int*   ap = adj + ((size_t)(b * M_ + row0 + lr)) * M_ + colbase + g * 8;
  const float* fp = f2 + b * M_ + colbase + g * 8;
  const u16*   hp = ht + ((size_t)b * FOUT_ + lr) * M_ + colbase + g * 8;
  const float f1r = f1[b * M_ + row0 + lr];

  f32x4 acc[8];
#pragma unroll
  for (int ft = 0; ft < 8; ++ft) acc[ft] = (f32x4){0.f, 0.f, 0.f, 0.f};
  float m = -INFINITY, lsum = 0.f;

  int4   ajE0, ajE1, ajO0, ajO1;              // adj double-parity bufs (depth 2)
  float4 fA0, fA1, fB0, fB1;                  // f2 ping-pong
  bf16x8 vA[8], vB[8];                        // V ping-pong

  // prologue: adj chunks 0,1; f2/V chunk 0
  ajE0 = *(const int4*)(ap);       ajE1 = *(const int4*)(ap + 4);
  ajO0 = *(const int4*)(ap + 32);  ajO1 = *(const int4*)(ap + 36);
  fA0  = *(const float4*)(fp);     fA1  = *(const float4*)(fp + 4);
#pragma unroll
  for (int ft = 0; ft < 8; ++ft) vA[ft] = *(const bf16x8*)(hp + (size_t)ft * 16 * M_);

  auto iter = [&](int c, int4& ajA, int4& ajB,
                  float4& fvA, float4& fvB, bf16x8 (&vC)[8],
                  float4& fnA, float4& fnB, bf16x8 (&vN)[8]) {
    // consume adj regs first (they get reloaded for c+2 below)
    const int aj[8] = {ajA.x, ajA.y, ajA.z, ajA.w, ajB.x, ajB.y, ajB.z, ajB.w};
    const float fv[8] = {fvA.x, fvA.y, fvA.z, fvA.w, fvB.x, fvB.y, fvB.z, fvB.w};
    // issue next-chunk loads (no barriers -> natural vmcnt overlap)
    const int cn = (c + 1) & 15;
    const int c2 = (c + 2) & 15;
    fnA = *(const float4*)(fp + cn * 32);
    fnB = *(const float4*)(fp + cn * 32 + 4);
#pragma unroll
    for (int ft = 0; ft < 8; ++ft)
      vN[ft] = *(const bf16x8*)(hp + (size_t)ft * 16 * M_ + cn * 32);
    ajA = *(const int4*)(ap + c2 * 32);
    ajB = *(const int4*)(ap + c2 * 32 + 4);
    // ---- scores (already in A-frag layout) ----
    float p[8];
    float pmax = -INFINITY;
#pragma unroll
    for (int i = 0; i < 8; ++i) {
      float z = f1r + fv[i];
      float e = z > 0.f ? z : ALPHA_ * z;
      float s = aj[i] > 0 ? e : NEG_INF_;
      p[i] = s;
      pmax = fmaxf(pmax, s);
    }
    pmax = fmaxf(pmax, __shfl_xor(pmax, 16));
    pmax = fmaxf(pmax, __shfl_xor(pmax, 32));
    // ---- defer-max online softmax (rescale rare, wave-uniform) ----
    if (!__all(pmax - m <= 8.f)) {
      const float mnew = fmaxf(m, pmax);
      const float scl  = __expf(m - mnew);   // first chunk: exp(-inf)=0
      m = mnew;
      lsum *= scl;
      f32x4 sv = { __shfl(scl, g * 4 + 0), __shfl(scl, g * 4 + 1),
                   __shfl(scl, g * 4 + 2), __shfl(scl, g * 4 + 3) };
#pragma unroll
      for (int ft = 0; ft < 8; ++ft) acc[ft] *= sv;
    }
    float psum = 0.f;
    bf16x8 af;
#pragma unroll
    for (int i = 0; i < 8; ++i) {
      float pe = __expf(p[i] - m);          // bounded by e^8
      psum += pe;
      af[i] = (short)f2bf(pe);
    }
    psum += __shfl_xor(psum, 16);
    psum += __shfl_xor(psum, 32);
    lsum += psum;
    // ---- PV MFMA: 8 frags, pure-register A, prefetched B ----
#pragma unroll
    for (int ft = 0; ft < 8; ++ft)
      acc[ft] = __builtin_amdgcn_mfma_f32_16x16x32_bf16(af, vC[ft], acc[ft], 0, 0, 0);
  };

#pragma unroll 1
  for (int cc = 0; cc < 16; cc += 2) {
    iter(cc,     ajE0, ajE1, fA0, fA1, vA, fB0, fB1, vB);
    iter(cc + 1, ajO0, ajO1, fB0, fB1, vB, fA0, fA1, vA);
  }

  // ---- epilogue: merge 4 col-quarter waves ----
  __shared__ float sm[4][16], sl[4][16];
  __shared__ float obuf[16][132];
  if (l < 16) { sm[w][l] = m; sl[w][l] = lsum; }
  __syncthreads();

  f32x4 fac;
#pragma unroll
  for (int j = 0; j < 4; ++j) {
    const int R = g * 4 + j;
    const float M4 = fmaxf(fmaxf(sm[0][R], sm[1][R]), fmaxf(sm[2][R], sm[3][R]));
    fac[j] = __expf(sm[w][R] - M4);
  }
#pragma unroll 1
  for (int wk = 0; wk < 4; ++wk) {
    if (w == wk) {
#pragma unroll
      for (int ft = 0; ft < 8; ++ft)
#pragma unroll
        for (int j = 0; j < 4; ++j) {
          if (wk == 0) obuf[g * 4 + j][ft * 16 + lr]  = acc[ft][j] * fac[j];
          else         obuf[g * 4 + j][ft * 16 + lr] += acc[ft][j] * fac[j];
        }
    }
    __syncthreads();
  }

  // final: thread t -> row tid>>4, feats (tid&15)*8..+7
  const int row = tid >> 4;
  const int f0  = (tid & 15) * 8;
  const float Mr = fmaxf(fmaxf(sm[0][row], sm[1][row]), fmaxf(sm[2][row], sm[3][row]));
  const float Lr = sl[0][row] * __expf(sm[0][row] - Mr) + sl[1][row] * __expf(sm[1][row] - Mr)
                 + sl[2][row] * __expf(sm[2][row] - Mr) + sl[3][row] * __expf(sm[3][row] - Mr);
  const float inv = 1.0f / Lr;
  float4 o0, o1;
  float t;
  t = obuf[row][f0 + 0] * inv; o0.x = t > 0.f ? t : __expf(t) - 1.f;
  t = obuf[row][f0 + 1] * inv; o0.y = t > 0.f ? t : __expf(t) - 1.f;
  t = obuf[row][f0 + 2] * inv; o0.z = t > 0.f ? t : __expf(t) - 1.f;
  t = obuf[row][f0 + 3] * inv; o0.w = t > 0.f ? t : __expf(t) - 1.f;
  t = obuf[row][f0 + 4] * inv; o1.x = t > 0.f ? t : __expf(t) - 1.f;
  t = obuf[row][f0 + 5] * inv; o1.y = t > 0.f ? t : __expf(t) - 1.f;
  t = obuf[row][f0 + 6] * inv; o1.z = t > 0.f ? t : __expf(t) - 1.f;
  t = obuf[row][f0 + 7] * inv; o1.w = t > 0.f ? t : __expf(t) - 1.f;
  float* op = out + ((size_t)b * M_ + row0 + row) * FOUT_ + f0;
  *(float4*)(op)     = o0;
  *(float4*)(op + 4) = o1;
}

extern "C" void kernel_launch(void* const* d_in, const int* in_sizes, int n_in,
                              void* d_out, int out_size, void* d_ws, size_t ws_size,
                              hipStream_t stream) {
  const float* x   = (const float*)d_in[0];
  const int*   adj = (const int*)d_in[1];
  const float* W   = (const float*)d_in[2];
  const float* a   = (const float*)d_in[3];
  float* out = (float*)d_out;

  char* ws = (char*)d_ws;
  u16*   Wt = (u16*)ws;                        // 64 KB
  float* f1 = (float*)(ws + 65536);            // 64 KB
  float* f2 = (float*)(ws + 131072);           // 64 KB
  u16*   ht = (u16*)(ws + 196608);             // 8.4 MB  [B][128][2048] bf16

  hipLaunchKernelGGL(k_wt,   dim3(128),  dim3(256), 0, stream, W, Wt);
  hipLaunchKernelGGL(k_xw,   dim3(1024), dim3(128), 0, stream, x, Wt, a, ht, f1, f2);
  hipLaunchKernelGGL(k_attn, dim3(1024), dim3(256), 0, stream, ht, adj, f1, f2, out);
}